// Round 15
// baseline (277.744 us; speedup 1.0000x reference)
//
#include <hip/hip_runtime.h>
#include <hip/hip_bf16.h>

typedef __attribute__((ext_vector_type(8))) short short8;
typedef __attribute__((ext_vector_type(4))) float f32x4;
typedef __attribute__((ext_vector_type(16))) float f32x16;
typedef unsigned short u16;
typedef unsigned int u32;

#define T_TOK 32768
#define CDIM  512
#define HEADS 8
#define HD    64
#define NSEQ  8192

#define AS1 __attribute__((address_space(1)))
#define AS3 __attribute__((address_space(3)))

__device__ __forceinline__ u16 f2bf(float f) {
  u32 u = __builtin_bit_cast(u32, f);
  u = u + 0x7fffu + ((u >> 16) & 1u);   // RNE
  return (u16)(u >> 16);
}
__device__ __forceinline__ float bf2f(u16 s) {
  return __builtin_bit_cast(float, ((u32)s) << 16);
}

// ---------------- K0: merged prep — pack weights bf16 + convert x bf16 -----------------
__global__ __launch_bounds__(256) void k_prep(const float* __restrict__ x,
    const float* __restrict__ Wq, const float* __restrict__ Wk,
    const float* __restrict__ Wv, const float* __restrict__ Wo,
    u16* __restrict__ Wcat, u16* __restrict__ xb) {
  int idx = blockIdx.x * 256 + threadIdx.x;      // 0..1048575
  {
    int c = idx & 511;
    int o2 = idx >> 9;
    const float* W = (o2 < 512) ? Wq : (o2 < 1024) ? Wk : (o2 < 1536) ? Wv : Wo;
    int o = o2 & 511;
    Wcat[idx] = f2bf(W[o * 512 + c]);
  }
  _Pragma("unroll")
  for (int r = 0; r < 2; ++r) {
    size_t i = (size_t)idx + (size_t)r * 1048576;   // over 2,097,152 units of 8 f32
    float4 a = *reinterpret_cast<const float4*>(&x[i * 8]);
    float4 b = *reinterpret_cast<const float4*>(&x[i * 8 + 4]);
    ushort4 r0, r1;
    r0.x = f2bf(a.x); r0.y = f2bf(a.y); r0.z = f2bf(a.z); r0.w = f2bf(a.w);
    r1.x = f2bf(b.x); r1.y = f2bf(b.y); r1.z = f2bf(b.z); r1.w = f2bf(b.w);
    *reinterpret_cast<ushort4*>(&xb[i * 8])     = r0;
    *reinterpret_cast<ushort4*>(&xb[i * 8 + 4]) = r1;
  }
}

// ---------------- K1/K5: 128^2-tile GEMM, 32x32x16 MFMA, 5 blocks/CU -------------------
// MODE 0: A=xb, B rows 0..1535, out=qkv bf16 stride 1536, elu+1 on q,k. NT=12.
// MODE 1: A=attn, B rows 1536..2047, out=f32 stride 512, bias b0. NT=4.
// r15: (a) launch_bounds(256,5) -> 5 blocks/CU (LDS 5x32KB = 160KB pool exactly; VGPR
// budget 409/wave, kernel uses ~128) — r11 A/B proved blocks/CU is the dominant lever.
// (b) 32x32x16 MFMA: 2382 vs 2075 TF ubench, half the MFMA instruction count, same
// ds_read bytes. A/B frag: row/col = l&31, kbase = (l>>5)*8 (standard extension of the
// verified 16x16 mapping). C/D (HW-verified m74/m101): col=l&31,
// row=(reg&3)+8*(reg>>2)+4*(l>>5). Read slot s = kstep*2+(l>>5), phys = s^(row&7) —
// per-bank 8 words/instr = b128 floor, conflict-free under the r3 involution swizzle.
template<int MODE>
__global__ __launch_bounds__(256, 5) void k_gemm(const u16* __restrict__ Ag,
    const u16* __restrict__ Wcat,
    const float* __restrict__ b0, const float* __restrict__ b1, const float* __restrict__ b2,
    u16* __restrict__ obf, float* __restrict__ of32) {
  constexpr int NT = (MODE == 0) ? 12 : 4;        // 128-wide n-tiles
  constexpr int BROW = (MODE == 0) ? 0 : 1536;    // Wcat row offset
  constexpr int OSTRIDE = (MODE == 0) ? 1536 : 512;
  __shared__ u16 As[128][64];
  __shared__ u16 Bs[128][64];
  int bid = blockIdx.x;
  constexpr int GRID = (T_TOK / 128) * NT;
  constexpr int CHUNK = GRID / 8;                 // blocks per XCD
  int swz = (bid & 7) * CHUNK + (bid >> 3);       // bijective: GRID % 8 == 0
  int m0 = (swz / NT) * 128;
  int n0 = (swz % NT) * 128;
  int tid = threadIdx.x;
  int lane = tid & 63, w = tid >> 6;
  int wr = w >> 1, wc = w & 1;
  f32x16 acc[2][2];                               // [mi][ni] 32x32 frags, 64 regs total
  _Pragma("unroll")
  for (int i = 0; i < 2; ++i)
    _Pragma("unroll")
    for (int j = 0; j < 2; ++j) acc[i][j] = (f32x16)0.0f;

  const u16* Bg = Wcat + (size_t)BROW * 512;
  int grl = lane >> 3;                  // lane's row within 8-row stripe
  int gcl = (((lane & 7) ^ grl)) * 8;   // pre-swizzled 16B slot (involution)
  int l31 = lane & 31, lhi5 = lane >> 5, sx = lane & 7;

  for (int t = 0; t < 8; ++t) {
    int k0 = t * 64;
    // stage A+B: wave w covers rows [w*32, w*32+32), 4 issues x 8 rows each, 16B/lane
    _Pragma("unroll")
    for (int i = 0; i < 4; ++i) {
      int r = w * 32 + i * 8;
      __builtin_amdgcn_global_load_lds(
          (const AS1 void*)&Ag[(size_t)(m0 + r + grl) * 512 + k0 + gcl],
          (AS3 void*)&As[r][0], 16, 0, 0);
      __builtin_amdgcn_global_load_lds(
          (const AS1 void*)&Bg[(size_t)(n0 + r + grl) * 512 + k0 + gcl],
          (AS3 void*)&Bs[r][0], 16, 0, 0);
    }
    __syncthreads();                    // vmcnt(0) drain; covered by 4 sibling blocks
    _Pragma("unroll")
    for (int kstep = 0; kstep < 4; ++kstep) {     // K=16 per MFMA
      int slot = (kstep * 2 + lhi5) ^ sx;         // read-side XOR (matches source perm)
      short8 af[2], bfr[2];
      _Pragma("unroll")
      for (int m = 0; m < 2; ++m)
        af[m] = *reinterpret_cast<const short8*>(&As[wr * 64 + m * 32 + l31][slot * 8]);
      _Pragma("unroll")
      for (int n = 0; n < 2; ++n)
        bfr[n] = *reinterpret_cast<const short8*>(&Bs[wc * 64 + n * 32 + l31][slot * 8]);
      _Pragma("unroll")
      for (int m = 0; m < 2; ++m)
        _Pragma("unroll")
        for (int n = 0; n < 2; ++n)
          acc[m][n] = __builtin_amdgcn_mfma_f32_32x32x16_bf16(af[m], bfr[n], acc[m][n], 0, 0, 0);
    }
    __syncthreads();                    // all waves done reading before next overwrite
  }

  // epilogue: C/D layout col=l&31, row=(reg&3)+8*(reg>>2)+4*(l>>5)
  _Pragma("unroll")
  for (int m = 0; m < 2; ++m) {
    _Pragma("unroll")
    for (int n = 0; n < 2; ++n) {
      int col = n0 + wc * 64 + n * 32 + l31;
      float bias;
      if (MODE == 0)
        bias = (col < 512) ? b0[col] : (col < 1024) ? b1[col - 512] : b2[col - 1024];
      else
        bias = b0[col];
      _Pragma("unroll")
      for (int r2 = 0; r2 < 4; ++r2) {
        int rowb = m0 + wr * 64 + m * 32 + r2 * 8 + lhi5 * 4;
        _Pragma("unroll")
        for (int j = 0; j < 4; ++j) {
          float vv = acc[m][n][r2 * 4 + j] + bias;
          if (MODE == 0) {
            if (col < 1024) vv = (vv > 0.0f) ? (vv + 1.0f) : __expf(vv);
            obf[(size_t)(rowb + j) * OSTRIDE + col] = f2bf(vv);
          } else {
            of32[(size_t)(rowb + j) * OSTRIDE + col] = vv;
          }
        }
      }
    }
  }
}

// ---------------- K2: per (head, K-split): partial kv[64][64] and ksum[64] -------------
__global__ __launch_bounds__(256) void k_kvstats(const u16* __restrict__ qkv,
    float* __restrict__ kvp, float* __restrict__ ksp) {
  __shared__ u16 kt[64][32];     // transposed: [d][t'] (swizzled)
  __shared__ u16 vt[64][32];     // transposed: [e][t'] (swizzled)
  __shared__ float ks_red[4][64];
  int hh = blockIdx.x;           // 0..31  (b*8+h)
  int s  = blockIdx.y;           // 0..15
  int b = hh >> 3, h = hh & 7;
  int tid = threadIdx.x;
  int lane = tid & 63, w = tid >> 6;
  size_t tbase = (size_t)b * NSEQ + (size_t)s * 512;
  f32x4 acc[4];
  for (int n = 0; n < 4; ++n) acc[n] = (f32x4)0.0f;
  float ksum_loc = 0.0f;
  int kcol = 512 + h * 64;
  int vcol = 1024 + h * 64;
  int l15 = lane & 15;
  int rsw = 8 * (l15 >> 2);            // read-side XOR for rows 16-aligned

  for (int step = 0; step < 16; ++step) {
    size_t t0 = tbase + (size_t)step * 32;
    for (int jj = 0; jj < 4; ++jj) {
      int id = tid + 256 * jj;           // 0..1023
      int trow = (id >> 4) & 31;
      int dq = id & 15;
      int isv = id >> 9;                 // 0: k-tile, 1: v-tile
      ushort4 val = *reinterpret_cast<const ushort4*>(
          &qkv[(t0 + trow) * 1536 + (isv ? vcol : kcol) + dq * 4]);
      u16 (*dst)[32] = isv ? vt : kt;
      int colw = trow ^ (8 * (dq & 3)); // store-side XOR: (d>>2)&3 == dq&3
      dst[dq * 4 + 0][colw] = val.x;
      dst[dq * 4 + 1][colw] = val.y;
      dst[dq * 4 + 2][colw] = val.z;
      dst[dq * 4 + 3][colw] = val.w;
    }
    __syncthreads();
    {   // ksum over this 32-token tile (logical col g*8+i -> physical XOR)
      int d = tid & 63, g = tid >> 6;
      int gs = 8 * (g ^ ((d >> 2) & 3));
      float sl = 0;
      for (int i = 0; i < 8; ++i) sl += bf2f(kt[d][gs + i]);
      ksum_loc += sl;
    }
    int kb = 8 * (lane >> 4);
    short8 af = *reinterpret_cast<const short8*>(&kt[w * 16 + l15][kb ^ rsw]);
    for (int n = 0; n < 4; ++n) {
      short8 bfr = *reinterpret_cast<const short8*>(&vt[n * 16 + l15][kb ^ rsw]);
      acc[n] = __builtin_amdgcn_mfma_f32_16x16x32_bf16(af, bfr, acc[n], 0, 0, 0);
    }
    __syncthreads();
  }
  size_t pbase = ((size_t)hh * 16 + s) * 4096;
  for (int n = 0; n < 4; ++n) {
    int d = w * 16 + (lane >> 4) * 4;
    int e = n * 16 + (lane & 15);
    for (int j = 0; j < 4; ++j)
      kvp[pbase + (size_t)(d + j) * 64 + e] = acc[n][j];
  }
  ks_red[tid >> 6][tid & 63] = ksum_loc;
  __syncthreads();
  if (tid < 64) {
    float r = ks_red[0][tid] + ks_red[1][tid] + ks_red[2][tid] + ks_red[3][tid];
    ksp[((size_t)hh * 16 + s) * 64 + tid] = r;
  }
}

// ---------------- K3: reduce split partials -> kv^T bf16 ([hh][e][d]) + ksum f32 -------
__global__ void k_reduce(const float* __restrict__ kvp, const float* __restrict__ ksp,
                         u16* __restrict__ kvb, float* __restrict__ ksum) {
  int hh = blockIdx.x;
  int sl = blockIdx.y;                // 0..7
  int tid = threadIdx.x;
  for (int j = 0; j < 2; ++j) {
    int idx = sl * 512 + tid + 256 * j;     // d*64+e
    float a = 0;
    for (int s = 0; s < 16; ++s) a += kvp[((size_t)hh * 16 + s) * 4096 + idx];
    int d = idx >> 6, e = idx & 63;
    kvb[(size_t)hh * 4096 + e * 64 + d] = f2bf(a);   // store transposed for B-fragments
  }
  if (sl == 0 && tid < 64) {
    float a = 0;
    for (int s = 0; s < 16; ++s) a += ksp[((size_t)hh * 16 + s) * 64 + tid];
    ksum[hh * 64 + tid] = a;
  }
}

// ---------------- K4: attn[t][512] = (q @ kv) / (q . ksum + eps), bf16 -----------------
__global__ __launch_bounds__(256) void k_attn(const u16* __restrict__ qkv,
    const u16* __restrict__ kvb, const float* __restrict__ ksum,
    u16* __restrict__ attn) {
  __shared__ u16 qf[32][520];
  __shared__ float zl[32][8];
  __shared__ float kss[8][64];
  int tid = threadIdx.x;
  int lane = tid & 63, w = tid >> 6;
  size_t t0 = (size_t)blockIdx.x * 32;
  int b = (int)(t0 >> 13);
  for (int jj = 0; jj < 16; ++jj) {
    int id = tid + 256 * jj;          // 0..4095
    int row = id >> 7, cq = id & 127;
    *reinterpret_cast<ushort4*>(&qf[row][cq * 4]) =
        *reinterpret_cast<const ushort4*>(&qkv[(t0 + row) * 1536 + cq * 4]);
  }
  { int i = tid, i2 = tid + 256;       // stage 512 ksum floats
    kss[i >> 6][i & 63]   = ksum[b * 512 + i];
    kss[i2 >> 6][i2 & 63] = ksum[b * 512 + i2]; }
  __syncthreads();
  {   // z per (token, head) — vectorized short8 reads
    int tok = tid & 31, h = tid >> 5;
    float z = 0;
    for (int jq = 0; jq < 8; ++jq) {
      short8 qv = *reinterpret_cast<const short8*>(&qf[tok][h * 64 + jq * 8]);
      for (int e = 0; e < 8; ++e) z += bf2f((u16)qv[e]) * kss[h][jq * 8 + e];
    }
    zl[tok][h] = z + 1e-6f;
  }
  __syncthreads();
  for (int hi = 0; hi < 2; ++hi) {
    int h = w * 2 + hi;
    size_t kvoff = (size_t)(b * 8 + h) * 4096;
    f32x4 acc[2][4];
    for (int m = 0; m < 2; ++m) for (int n = 0; n < 4; ++n) acc[m][n] = (f32x4)0.0f;
    for (int kk = 0; kk < 2; ++kk) {
      int kb = kk * 32 + 8 * (lane >> 4);
      short8 af[2], bfr[4];
      for (int m = 0; m < 2; ++m)
        af[m] = *reinterpret_cast<const short8*>(&qf[m * 16 + (lane & 15)][h * 64 + kb]);
      for (int n = 0; n < 4; ++n)
        bfr[n] = *reinterpret_cast<const short8*>(&kvb[kvoff + (size_t)(n * 16 + (lane & 15)) * 64 + kb]);
      for (int m = 0; m < 2; ++m)
        for (int n = 0; n < 4; ++n)
          acc[m][n] = __builtin_amdgcn_mfma_f32_16x16x32_bf16(af[m], bfr[n], acc[m][n], 0, 0, 0);
    }
    for (int m = 0; m < 2; ++m) {
      int tokb = m * 16 + (lane >> 4) * 4;
      for (int n = 0; n < 4; ++n) {
        int e = n * 16 + (lane & 15);
        for (int j = 0; j < 4; ++j) {
          float vv = acc[m][n][j] / zl[tokb + j][h];
          attn[(t0 + tokb + j) * 512 + h * 64 + e] = f2bf(vv);
        }
      }
    }
  }
}

extern "C" void kernel_launch(void* const* d_in, const int* in_sizes, int n_in,
                              void* d_out, int out_size, void* d_ws, size_t ws_size,
                              hipStream_t stream) {
  const float* x  = (const float*)d_in[0];
  const float* Wq = (const float*)d_in[1];
  const float* bq = (const float*)d_in[2];
  const float* Wk = (const float*)d_in[3];
  const float* bk = (const float*)d_in[4];
  const float* Wv = (const float*)d_in[5];
  const float* bv = (const float*)d_in[6];
  const float* Wo = (const float*)d_in[7];
  const float* bo = (const float*)d_in[8];
  float* out = (float*)d_out;

  char* ws = (char*)d_ws;
  u16*   Wcat = (u16*)(ws + 0);                 //   2,097,152 B
  u16*   qkv  = (u16*)(ws + 2097152);           // 100,663,296 B
  // Region at 102,760,448 is time-shared (strict stream order):
  //   xb   (33.5 MB)  written by k_prep, read by gemm<0>
  //   kvp  ( 8.4 MB)  written by kvstats (after gemm<0>), read by reduce
  //   attn (33.5 MB)  written by k_attn (after reduce), read by gemm<1>
  u16*   xb   = (u16*)(ws + 102760448);
  float* kvp  = (float*)(ws + 102760448);
  u16*   attn = (u16*)(ws + 102760448);
  float* ksp  = (float*)(ws + 136314880);       //     131,072 B
  u16*   kvb  = (u16*)(ws + 136445952);         //     262,144 B
  float* ksum = (float*)(ws + 136708096);       //       8,192 B   (peak ~130.4 MiB)

  k_prep   <<<4096, 256, 0, stream>>>(x, Wq, Wk, Wv, Wo, Wcat, xb);
  k_gemm<0><<<3072, 256, 0, stream>>>(xb, Wcat, bq, bk, bv, qkv, nullptr);
  k_kvstats<<<dim3(32, 16), 256, 0, stream>>>(qkv, kvp, ksp);
  k_reduce <<<dim3(32, 8), 256, 0, stream>>>(kvp, ksp, kvb, ksum);
  k_attn   <<<1024, 256, 0, stream>>>(qkv, kvb, ksum, attn);
  k_gemm<1><<<1024, 256, 0, stream>>>(attn, Wcat, bo, nullptr, nullptr, nullptr, out);
}

// Round 16
// 158.235 us; speedup vs baseline: 1.7553x; 1.7553x over previous
//
#include <hip/hip_runtime.h>
#include <hip/hip_bf16.h>

typedef __attribute__((ext_vector_type(8))) short short8;
typedef __attribute__((ext_vector_type(4))) float f32x4;
typedef __attribute__((ext_vector_type(16))) float f32x16;
typedef unsigned short u16;
typedef unsigned int u32;

#define T_TOK 32768
#define CDIM  512
#define HEADS 8
#define HD    64
#define NSEQ  8192

#define AS1 __attribute__((address_space(1)))
#define AS3 __attribute__((address_space(3)))

__device__ __forceinline__ u16 f2bf(float f) {
  u32 u = __builtin_bit_cast(u32, f);
  u = u + 0x7fffu + ((u >> 16) & 1u);   // RNE
  return (u16)(u >> 16);
}
__device__ __forceinline__ float bf2f(u16 s) {
  return __builtin_bit_cast(float, ((u32)s) << 16);
}

// ---------------- K0: merged prep — pack weights bf16 + convert x bf16 -----------------
__global__ __launch_bounds__(256) void k_prep(const float* __restrict__ x,
    const float* __restrict__ Wq, const float* __restrict__ Wk,
    const float* __restrict__ Wv, const float* __restrict__ Wo,
    u16* __restrict__ Wcat, u16* __restrict__ xb) {
  int idx = blockIdx.x * 256 + threadIdx.x;      // 0..1048575
  {
    int c = idx & 511;
    int o2 = idx >> 9;
    const float* W = (o2 < 512) ? Wq : (o2 < 1024) ? Wk : (o2 < 1536) ? Wv : Wo;
    int o = o2 & 511;
    Wcat[idx] = f2bf(W[o * 512 + c]);
  }
  _Pragma("unroll")
  for (int r = 0; r < 2; ++r) {
    size_t i = (size_t)idx + (size_t)r * 1048576;   // over 2,097,152 units of 8 f32
    float4 a = *reinterpret_cast<const float4*>(&x[i * 8]);
    float4 b = *reinterpret_cast<const float4*>(&x[i * 8 + 4]);
    ushort4 r0, r1;
    r0.x = f2bf(a.x); r0.y = f2bf(a.y); r0.z = f2bf(a.z); r0.w = f2bf(a.w);
    r1.x = f2bf(b.x); r1.y = f2bf(b.y); r1.z = f2bf(b.z); r1.w = f2bf(b.w);
    *reinterpret_cast<ushort4*>(&xb[i * 8])     = r0;
    *reinterpret_cast<ushort4*>(&xb[i * 8 + 4]) = r1;
  }
}

// ---------------- K1/K5: 128^2-tile GEMM, 32x32x16 MFMA, 4 blocks/CU -------------------
// MODE 0: A=xb, B rows 0..1535, out=qkv bf16 stride 1536, elu+1 on q,k. NT=12.
// MODE 1: A=attn, B rows 1536..2047, out=f32 stride 512, bias b0. NT=4.
// r16: ISOLATED change vs r14 — 32x32x16 MFMA (2382 vs 2075 TF ubench; half the MFMA
// instruction count) at the PROVEN launch_bounds(256,4) occupancy. r15's regression was
// the (256,5) VGPR clamp to 48 (spill), NOT the 32x32 layout: correctness passed there
// (layout HW-verified), and reg math here is 64 acc + 16 ops + ~25 addr < 128 budget.
// Read pattern slot=(kstep*2+lhi5)^sx gives 8 words/bank/instr = b128 floor.
// A/B frag: row/col=l&31, kbase=(l>>5)*8. C/D: col=l&31, row=(reg&3)+8*(reg>>2)+4*(l>>5).
template<int MODE>
__global__ __launch_bounds__(256, 4) void k_gemm(const u16* __restrict__ Ag,
    const u16* __restrict__ Wcat,
    const float* __restrict__ b0, const float* __restrict__ b1, const float* __restrict__ b2,
    u16* __restrict__ obf, float* __restrict__ of32) {
  constexpr int NT = (MODE == 0) ? 12 : 4;        // 128-wide n-tiles
  constexpr int BROW = (MODE == 0) ? 0 : 1536;    // Wcat row offset
  constexpr int OSTRIDE = (MODE == 0) ? 1536 : 512;
  __shared__ u16 As[128][64];
  __shared__ u16 Bs[128][64];
  int bid = blockIdx.x;
  constexpr int GRID = (T_TOK / 128) * NT;
  constexpr int CHUNK = GRID / 8;                 // blocks per XCD
  int swz = (bid & 7) * CHUNK + (bid >> 3);       // bijective: GRID % 8 == 0
  int m0 = (swz / NT) * 128;
  int n0 = (swz % NT) * 128;
  int tid = threadIdx.x;
  int lane = tid & 63, w = tid >> 6;
  int wr = w >> 1, wc = w & 1;
  f32x16 acc[2][2];                               // [mi][ni] 32x32 frags, 64 regs total
  _Pragma("unroll")
  for (int i = 0; i < 2; ++i)
    _Pragma("unroll")
    for (int j = 0; j < 2; ++j) acc[i][j] = (f32x16)0.0f;

  const u16* Bg = Wcat + (size_t)BROW * 512;
  int grl = lane >> 3;                  // lane's row within 8-row stripe
  int gcl = (((lane & 7) ^ grl)) * 8;   // pre-swizzled 16B slot (involution)
  int l31 = lane & 31, lhi5 = lane >> 5, sx = lane & 7;

  for (int t = 0; t < 8; ++t) {
    int k0 = t * 64;
    // stage A+B: wave w covers rows [w*32, w*32+32), 4 issues x 8 rows each, 16B/lane
    _Pragma("unroll")
    for (int i = 0; i < 4; ++i) {
      int r = w * 32 + i * 8;
      __builtin_amdgcn_global_load_lds(
          (const AS1 void*)&Ag[(size_t)(m0 + r + grl) * 512 + k0 + gcl],
          (AS3 void*)&As[r][0], 16, 0, 0);
      __builtin_amdgcn_global_load_lds(
          (const AS1 void*)&Bg[(size_t)(n0 + r + grl) * 512 + k0 + gcl],
          (AS3 void*)&Bs[r][0], 16, 0, 0);
    }
    __syncthreads();                    // vmcnt(0) drain; covered by 3 sibling blocks
    _Pragma("unroll")
    for (int kstep = 0; kstep < 4; ++kstep) {     // K=16 per MFMA
      int slot = (kstep * 2 + lhi5) ^ sx;         // read-side XOR (matches source perm)
      short8 af[2], bfr[2];
      _Pragma("unroll")
      for (int m = 0; m < 2; ++m)
        af[m] = *reinterpret_cast<const short8*>(&As[wr * 64 + m * 32 + l31][slot * 8]);
      _Pragma("unroll")
      for (int n = 0; n < 2; ++n)
        bfr[n] = *reinterpret_cast<const short8*>(&Bs[wc * 64 + n * 32 + l31][slot * 8]);
      _Pragma("unroll")
      for (int m = 0; m < 2; ++m)
        _Pragma("unroll")
        for (int n = 0; n < 2; ++n)
          acc[m][n] = __builtin_amdgcn_mfma_f32_32x32x16_bf16(af[m], bfr[n], acc[m][n], 0, 0, 0);
    }
    __syncthreads();                    // all waves done reading before next overwrite
  }

  // epilogue: C/D layout col=l&31, row=(reg&3)+8*(reg>>2)+4*(l>>5)
  _Pragma("unroll")
  for (int m = 0; m < 2; ++m) {
    _Pragma("unroll")
    for (int n = 0; n < 2; ++n) {
      int col = n0 + wc * 64 + n * 32 + l31;
      float bias;
      if (MODE == 0)
        bias = (col < 512) ? b0[col] : (col < 1024) ? b1[col - 512] : b2[col - 1024];
      else
        bias = b0[col];
      _Pragma("unroll")
      for (int r2 = 0; r2 < 4; ++r2) {
        int rowb = m0 + wr * 64 + m * 32 + r2 * 8 + lhi5 * 4;
        _Pragma("unroll")
        for (int j = 0; j < 4; ++j) {
          float vv = acc[m][n][r2 * 4 + j] + bias;
          if (MODE == 0) {
            if (col < 1024) vv = (vv > 0.0f) ? (vv + 1.0f) : __expf(vv);
            obf[(size_t)(rowb + j) * OSTRIDE + col] = f2bf(vv);
          } else {
            of32[(size_t)(rowb + j) * OSTRIDE + col] = vv;
          }
        }
      }
    }
  }
}

// ---------------- K2: per (head, K-split): partial kv[64][64] and ksum[64] -------------
__global__ __launch_bounds__(256) void k_kvstats(const u16* __restrict__ qkv,
    float* __restrict__ kvp, float* __restrict__ ksp) {
  __shared__ u16 kt[64][32];     // transposed: [d][t'] (swizzled)
  __shared__ u16 vt[64][32];     // transposed: [e][t'] (swizzled)
  __shared__ float ks_red[4][64];
  int hh = blockIdx.x;           // 0..31  (b*8+h)
  int s  = blockIdx.y;           // 0..15
  int b = hh >> 3, h = hh & 7;
  int tid = threadIdx.x;
  int lane = tid & 63, w = tid >> 6;
  size_t tbase = (size_t)b * NSEQ + (size_t)s * 512;
  f32x4 acc[4];
  for (int n = 0; n < 4; ++n) acc[n] = (f32x4)0.0f;
  float ksum_loc = 0.0f;
  int kcol = 512 + h * 64;
  int vcol = 1024 + h * 64;
  int l15 = lane & 15;
  int rsw = 8 * (l15 >> 2);            // read-side XOR for rows 16-aligned

  for (int step = 0; step < 16; ++step) {
    size_t t0 = tbase + (size_t)step * 32;
    for (int jj = 0; jj < 4; ++jj) {
      int id = tid + 256 * jj;           // 0..1023
      int trow = (id >> 4) & 31;
      int dq = id & 15;
      int isv = id >> 9;                 // 0: k-tile, 1: v-tile
      ushort4 val = *reinterpret_cast<const ushort4*>(
          &qkv[(t0 + trow) * 1536 + (isv ? vcol : kcol) + dq * 4]);
      u16 (*dst)[32] = isv ? vt : kt;
      int colw = trow ^ (8 * (dq & 3)); // store-side XOR: (d>>2)&3 == dq&3
      dst[dq * 4 + 0][colw] = val.x;
      dst[dq * 4 + 1][colw] = val.y;
      dst[dq * 4 + 2][colw] = val.z;
      dst[dq * 4 + 3][colw] = val.w;
    }
    __syncthreads();
    {   // ksum over this 32-token tile (logical col g*8+i -> physical XOR)
      int d = tid & 63, g = tid >> 6;
      int gs = 8 * (g ^ ((d >> 2) & 3));
      float sl = 0;
      for (int i = 0; i < 8; ++i) sl += bf2f(kt[d][gs + i]);
      ksum_loc += sl;
    }
    int kb = 8 * (lane >> 4);
    short8 af = *reinterpret_cast<const short8*>(&kt[w * 16 + l15][kb ^ rsw]);
    for (int n = 0; n < 4; ++n) {
      short8 bfr = *reinterpret_cast<const short8*>(&vt[n * 16 + l15][kb ^ rsw]);
      acc[n] = __builtin_amdgcn_mfma_f32_16x16x32_bf16(af, bfr, acc[n], 0, 0, 0);
    }
    __syncthreads();
  }
  size_t pbase = ((size_t)hh * 16 + s) * 4096;
  for (int n = 0; n < 4; ++n) {
    int d = w * 16 + (lane >> 4) * 4;
    int e = n * 16 + (lane & 15);
    for (int j = 0; j < 4; ++j)
      kvp[pbase + (size_t)(d + j) * 64 + e] = acc[n][j];
  }
  ks_red[tid >> 6][tid & 63] = ksum_loc;
  __syncthreads();
  if (tid < 64) {
    float r = ks_red[0][tid] + ks_red[1][tid] + ks_red[2][tid] + ks_red[3][tid];
    ksp[((size_t)hh * 16 + s) * 64 + tid] = r;
  }
}

// ---------------- K3: reduce split partials -> kv^T bf16 ([hh][e][d]) + ksum f32 -------
__global__ void k_reduce(const float* __restrict__ kvp, const float* __restrict__ ksp,
                         u16* __restrict__ kvb, float* __restrict__ ksum) {
  int hh = blockIdx.x;
  int sl = blockIdx.y;                // 0..7
  int tid = threadIdx.x;
  for (int j = 0; j < 2; ++j) {
    int idx = sl * 512 + tid + 256 * j;     // d*64+e
    float a = 0;
    for (int s = 0; s < 16; ++s) a += kvp[((size_t)hh * 16 + s) * 4096 + idx];
    int d = idx >> 6, e = idx & 63;
    kvb[(size_t)hh * 4096 + e * 64 + d] = f2bf(a);   // store transposed for B-fragments
  }
  if (sl == 0 && tid < 64) {
    float a = 0;
    for (int s = 0; s < 16; ++s) a += ksp[((size_t)hh * 16 + s) * 64 + tid];
    ksum[hh * 64 + tid] = a;
  }
}

// ---------------- K4: attn[t][512] = (q @ kv) / (q . ksum + eps), bf16 -----------------
__global__ __launch_bounds__(256) void k_attn(const u16* __restrict__ qkv,
    const u16* __restrict__ kvb, const float* __restrict__ ksum,
    u16* __restrict__ attn) {
  __shared__ u16 qf[32][520];
  __shared__ float zl[32][8];
  __shared__ float kss[8][64];
  int tid = threadIdx.x;
  int lane = tid & 63, w = tid >> 6;
  size_t t0 = (size_t)blockIdx.x * 32;
  int b = (int)(t0 >> 13);
  for (int jj = 0; jj < 16; ++jj) {
    int id = tid + 256 * jj;          // 0..4095
    int row = id >> 7, cq = id & 127;
    *reinterpret_cast<ushort4*>(&qf[row][cq * 4]) =
        *reinterpret_cast<const ushort4*>(&qkv[(t0 + row) * 1536 + cq * 4]);
  }
  { int i = tid, i2 = tid + 256;       // stage 512 ksum floats
    kss[i >> 6][i & 63]   = ksum[b * 512 + i];
    kss[i2 >> 6][i2 & 63] = ksum[b * 512 + i2]; }
  __syncthreads();
  {   // z per (token, head) — vectorized short8 reads
    int tok = tid & 31, h = tid >> 5;
    float z = 0;
    for (int jq = 0; jq < 8; ++jq) {
      short8 qv = *reinterpret_cast<const short8*>(&qf[tok][h * 64 + jq * 8]);
      for (int e = 0; e < 8; ++e) z += bf2f((u16)qv[e]) * kss[h][jq * 8 + e];
    }
    zl[tok][h] = z + 1e-6f;
  }
  __syncthreads();
  for (int hi = 0; hi < 2; ++hi) {
    int h = w * 2 + hi;
    size_t kvoff = (size_t)(b * 8 + h) * 4096;
    f32x4 acc[2][4];
    for (int m = 0; m < 2; ++m) for (int n = 0; n < 4; ++n) acc[m][n] = (f32x4)0.0f;
    for (int kk = 0; kk < 2; ++kk) {
      int kb = kk * 32 + 8 * (lane >> 4);
      short8 af[2], bfr[4];
      for (int m = 0; m < 2; ++m)
        af[m] = *reinterpret_cast<const short8*>(&qf[m * 16 + (lane & 15)][h * 64 + kb]);
      for (int n = 0; n < 4; ++n)
        bfr[n] = *reinterpret_cast<const short8*>(&kvb[kvoff + (size_t)(n * 16 + (lane & 15)) * 64 + kb]);
      for (int m = 0; m < 2; ++m)
        for (int n = 0; n < 4; ++n)
          acc[m][n] = __builtin_amdgcn_mfma_f32_16x16x32_bf16(af[m], bfr[n], acc[m][n], 0, 0, 0);
    }
    for (int m = 0; m < 2; ++m) {
      int tokb = m * 16 + (lane >> 4) * 4;
      for (int n = 0; n < 4; ++n) {
        int e = n * 16 + (lane & 15);
        for (int j = 0; j < 4; ++j) {
          float vv = acc[m][n][j] / zl[tokb + j][h];
          attn[(t0 + tokb + j) * 512 + h * 64 + e] = f2bf(vv);
        }
      }
    }
  }
}

extern "C" void kernel_launch(void* const* d_in, const int* in_sizes, int n_in,
                              void* d_out, int out_size, void* d_ws, size_t ws_size,
                              hipStream_t stream) {
  const float* x  = (const float*)d_in[0];
  const float* Wq = (const float*)d_in[1];
  const float* bq = (const float*)d_in[2];
  const float* Wk = (const float*)d_in[3];
  const float* bk = (const float*)d_in[4];
  const float* Wv = (const float*)d_in[5];
  const float* bv = (const float*)d_in[6];
  const float* Wo = (const float*)d_in[7];
  const float* bo = (const float*)d_in[8];
  float* out = (float*)d_out;

  char* ws = (char*)d_ws;
  u16*   Wcat = (u16*)(ws + 0);                 //   2,097,152 B
  u16*   qkv  = (u16*)(ws + 2097152);           // 100,663,296 B
  // Region at 102,760,448 is time-shared (strict stream order):
  //   xb   (33.5 MB)  written by k_prep, read by gemm<0>
  //   kvp  ( 8.4 MB)  written by kvstats (after gemm<0>), read by reduce
  //   attn (33.5 MB)  written by k_attn (after reduce), read by gemm<1>
  u16*   xb   = (u16*)(ws + 102760448);
  float* kvp  = (float*)(ws + 102760448);
  u16*   attn = (u16*)(ws + 102760448);
  float* ksp  = (float*)(ws + 136314880);       //     131,072 B
  u16*   kvb  = (u16*)(ws + 136445952);         //     262,144 B
  float* ksum = (float*)(ws + 136708096);       //       8,192 B   (peak ~130.4 MiB)

  k_prep   <<<4096, 256, 0, stream>>>(x, Wq, Wk, Wv, Wo, Wcat, xb);
  k_gemm<0><<<3072, 256, 0, stream>>>(xb, Wcat, bq, bk, bv, qkv, nullptr);
  k_kvstats<<<dim3(32, 16), 256, 0, stream>>>(qkv, kvp, ksp);
  k_reduce <<<dim3(32, 8), 256, 0, stream>>>(kvp, ksp, kvb, ksum);
  k_attn   <<<1024, 256, 0, stream>>>(qkv, kvb, ksum, attn);
  k_gemm<1><<<1024, 256, 0, stream>>>(attn, Wcat, bo, nullptr, nullptr, nullptr, out);
}

// Round 17
// 155.571 us; speedup vs baseline: 1.7853x; 1.0171x over previous
//
#include <hip/hip_runtime.h>
#include <hip/hip_bf16.h>

typedef __attribute__((ext_vector_type(8))) short short8;
typedef __attribute__((ext_vector_type(4))) float f32x4;
typedef unsigned short u16;
typedef unsigned int u32;

#define T_TOK 32768
#define CDIM  512
#define HEADS 8
#define HD    64
#define NSEQ  8192

#define AS1 __attribute__((address_space(1)))
#define AS3 __attribute__((address_space(3)))

__device__ __forceinline__ u16 f2bf(float f) {
  u32 u = __builtin_bit_cast(u32, f);
  u = u + 0x7fffu + ((u >> 16) & 1u);   // RNE
  return (u16)(u >> 16);
}
__device__ __forceinline__ float bf2f(u16 s) {
  return __builtin_bit_cast(float, ((u32)s) << 16);
}

// ---------------- K0: merged prep — pack weights bf16 + convert x bf16 -----------------
__global__ __launch_bounds__(256) void k_prep(const float* __restrict__ x,
    const float* __restrict__ Wq, const float* __restrict__ Wk,
    const float* __restrict__ Wv, const float* __restrict__ Wo,
    u16* __restrict__ Wcat, u16* __restrict__ xb) {
  int idx = blockIdx.x * 256 + threadIdx.x;      // 0..1048575
  {
    int c = idx & 511;
    int o2 = idx >> 9;
    const float* W = (o2 < 512) ? Wq : (o2 < 1024) ? Wk : (o2 < 1536) ? Wv : Wo;
    int o = o2 & 511;
    Wcat[idx] = f2bf(W[o * 512 + c]);
  }
  _Pragma("unroll")
  for (int r = 0; r < 2; ++r) {
    size_t i = (size_t)idx + (size_t)r * 1048576;   // over 2,097,152 units of 8 f32
    float4 a = *reinterpret_cast<const float4*>(&x[i * 8]);
    float4 b = *reinterpret_cast<const float4*>(&x[i * 8 + 4]);
    ushort4 r0, r1;
    r0.x = f2bf(a.x); r0.y = f2bf(a.y); r0.z = f2bf(a.z); r0.w = f2bf(a.w);
    r1.x = f2bf(b.x); r1.y = f2bf(b.y); r1.z = f2bf(b.z); r1.w = f2bf(b.w);
    *reinterpret_cast<ushort4*>(&xb[i * 8])     = r0;
    *reinterpret_cast<ushort4*>(&xb[i * 8 + 4]) = r1;
  }
}

// ---------------- K1/K5: 128^2-tile, 4-blocks/CU GEMM  out = A @ Wsec^T ----------------
// MODE 0: A=xb, B rows 0..1535, out=qkv bf16 stride 1536, elu+1 on q,k. NT=12.
// MODE 1: A=attn, B rows 1536..2047, out=f32 stride 512, bias b0. NT=4.
// SESSION OPTIMUM (r11/r14, 66.4us = 776 TF): 256 thr (4 waves, 2x2), 32 KB
// single-buffer LDS, launch_bounds(256,4) -> 4 blocks/CU cross-covering barrier drains.
// Departures all measured WORSE and understood:
//   r12 fat-tile (2 blk/CU) 80us; r13 fused conv staging (VGPR-starved) 166us;
//   r15 (256,5) VGPR clamp->spill 192us; r15/r16 32x32x16 MFMA: quarter-wave 4-way
//   LDS conflicts (6.29M) + partial-sector epilogue writes, 70.7us;
//   r6/r7 counted-vmcnt/8-phase at 1 blk/CU: 85-92us (no sibling coverage).
// Do not reg-stage anything here (register budget = 64 VGPR + 64 AGPR acc, exact).
// r3-proven involution swizzle (measured SQ_LDS_BANK_CONFLICT=0). No setprio (m190).
template<int MODE>
__global__ __launch_bounds__(256, 4) void k_gemm(const u16* __restrict__ Ag,
    const u16* __restrict__ Wcat,
    const float* __restrict__ b0, const float* __restrict__ b1, const float* __restrict__ b2,
    u16* __restrict__ obf, float* __restrict__ of32) {
  constexpr int NT = (MODE == 0) ? 12 : 4;        // 128-wide n-tiles
  constexpr int BROW = (MODE == 0) ? 0 : 1536;    // Wcat row offset
  constexpr int OSTRIDE = (MODE == 0) ? 1536 : 512;
  __shared__ u16 As[128][64];
  __shared__ u16 Bs[128][64];
  int bid = blockIdx.x;
  constexpr int GRID = (T_TOK / 128) * NT;
  constexpr int CHUNK = GRID / 8;                 // blocks per XCD
  int swz = (bid & 7) * CHUNK + (bid >> 3);       // bijective: GRID % 8 == 0
  int m0 = (swz / NT) * 128;
  int n0 = (swz % NT) * 128;
  int tid = threadIdx.x;
  int lane = tid & 63, w = tid >> 6;
  int wr = w >> 1, wc = w & 1;
  f32x4 acc[4][4];
  _Pragma("unroll")
  for (int i = 0; i < 4; ++i)
    _Pragma("unroll")
    for (int j = 0; j < 4; ++j) acc[i][j] = (f32x4)0.0f;

  const u16* Bg = Wcat + (size_t)BROW * 512;
  int grl = lane >> 3;                  // lane's row within 8-row stripe
  int gcl = (((lane & 7) ^ grl)) * 8;   // pre-swizzled 16B slot (involution)
  int l15 = lane & 15, lhi = lane >> 4, sx = lane & 7;

  for (int t = 0; t < 8; ++t) {
    int k0 = t * 64;
    // stage A+B: wave w covers rows [w*32, w*32+32), 4 issues x 8 rows each, 16B/lane
    _Pragma("unroll")
    for (int i = 0; i < 4; ++i) {
      int r = w * 32 + i * 8;
      __builtin_amdgcn_global_load_lds(
          (const AS1 void*)&Ag[(size_t)(m0 + r + grl) * 512 + k0 + gcl],
          (AS3 void*)&As[r][0], 16, 0, 0);
      __builtin_amdgcn_global_load_lds(
          (const AS1 void*)&Bg[(size_t)(n0 + r + grl) * 512 + k0 + gcl],
          (AS3 void*)&Bs[r][0], 16, 0, 0);
    }
    __syncthreads();                    // vmcnt(0) drain; covered by 3 sibling blocks
    _Pragma("unroll")
    for (int kk = 0; kk < 2; ++kk) {
      int slot = (kk * 4 + lhi) ^ sx;   // read-side XOR (matches source permutation)
      short8 af[4], bfr[4];
      _Pragma("unroll")
      for (int m = 0; m < 4; ++m)
        af[m] = *reinterpret_cast<const short8*>(&As[wr * 64 + m * 16 + l15][slot * 8]);
      _Pragma("unroll")
      for (int n = 0; n < 4; ++n)
        bfr[n] = *reinterpret_cast<const short8*>(&Bs[wc * 64 + n * 16 + l15][slot * 8]);
      _Pragma("unroll")
      for (int m = 0; m < 4; ++m)
        _Pragma("unroll")
        for (int n = 0; n < 4; ++n)
          acc[m][n] = __builtin_amdgcn_mfma_f32_16x16x32_bf16(af[m], bfr[n], acc[m][n], 0, 0, 0);
    }
    __syncthreads();                    // all waves done reading before next overwrite
  }

  _Pragma("unroll")
  for (int m = 0; m < 4; ++m) {
    int row = m0 + wr * 64 + m * 16 + lhi * 4;
    _Pragma("unroll")
    for (int n = 0; n < 4; ++n) {
      int col = n0 + wc * 64 + n * 16 + l15;
      float bias;
      if (MODE == 0)
        bias = (col < 512) ? b0[col] : (col < 1024) ? b1[col - 512] : b2[col - 1024];
      else
        bias = b0[col];
      _Pragma("unroll")
      for (int j = 0; j < 4; ++j) {
        float vv = acc[m][n][j] + bias;
        if (MODE == 0) {
          if (col < 1024) vv = (vv > 0.0f) ? (vv + 1.0f) : __expf(vv);
          obf[(size_t)(row + j) * OSTRIDE + col] = f2bf(vv);
        } else {
          of32[(size_t)(row + j) * OSTRIDE + col] = vv;
        }
      }
    }
  }
}

// ---------------- K2: per (head, K-split): partial kv[64][64] and ksum[64] -------------
__global__ __launch_bounds__(256) void k_kvstats(const u16* __restrict__ qkv,
    float* __restrict__ kvp, float* __restrict__ ksp) {
  __shared__ u16 kt[64][32];     // transposed: [d][t'] (swizzled)
  __shared__ u16 vt[64][32];     // transposed: [e][t'] (swizzled)
  __shared__ float ks_red[4][64];
  int hh = blockIdx.x;           // 0..31  (b*8+h)
  int s  = blockIdx.y;           // 0..15
  int b = hh >> 3, h = hh & 7;
  int tid = threadIdx.x;
  int lane = tid & 63, w = tid >> 6;
  size_t tbase = (size_t)b * NSEQ + (size_t)s * 512;
  f32x4 acc[4];
  for (int n = 0; n < 4; ++n) acc[n] = (f32x4)0.0f;
  float ksum_loc = 0.0f;
  int kcol = 512 + h * 64;
  int vcol = 1024 + h * 64;
  int l15 = lane & 15;
  int rsw = 8 * (l15 >> 2);            // read-side XOR for rows 16-aligned

  for (int step = 0; step < 16; ++step) {
    size_t t0 = tbase + (size_t)step * 32;
    for (int jj = 0; jj < 4; ++jj) {
      int id = tid + 256 * jj;           // 0..1023
      int trow = (id >> 4) & 31;
      int dq = id & 15;
      int isv = id >> 9;                 // 0: k-tile, 1: v-tile
      ushort4 val = *reinterpret_cast<const ushort4*>(
          &qkv[(t0 + trow) * 1536 + (isv ? vcol : kcol) + dq * 4]);
      u16 (*dst)[32] = isv ? vt : kt;
      int colw = trow ^ (8 * (dq & 3)); // store-side XOR: (d>>2)&3 == dq&3
      dst[dq * 4 + 0][colw] = val.x;
      dst[dq * 4 + 1][colw] = val.y;
      dst[dq * 4 + 2][colw] = val.z;
      dst[dq * 4 + 3][colw] = val.w;
    }
    __syncthreads();
    {   // ksum over this 32-token tile (logical col g*8+i -> physical XOR)
      int d = tid & 63, g = tid >> 6;
      int gs = 8 * (g ^ ((d >> 2) & 3));
      float sl = 0;
      for (int i = 0; i < 8; ++i) sl += bf2f(kt[d][gs + i]);
      ksum_loc += sl;
    }
    int kb = 8 * (lane >> 4);
    short8 af = *reinterpret_cast<const short8*>(&kt[w * 16 + l15][kb ^ rsw]);
    for (int n = 0; n < 4; ++n) {
      short8 bfr = *reinterpret_cast<const short8*>(&vt[n * 16 + l15][kb ^ rsw]);
      acc[n] = __builtin_amdgcn_mfma_f32_16x16x32_bf16(af, bfr, acc[n], 0, 0, 0);
    }
    __syncthreads();
  }
  size_t pbase = ((size_t)hh * 16 + s) * 4096;
  for (int n = 0; n < 4; ++n) {
    int d = w * 16 + (lane >> 4) * 4;
    int e = n * 16 + (lane & 15);
    for (int j = 0; j < 4; ++j)
      kvp[pbase + (size_t)(d + j) * 64 + e] = acc[n][j];
  }
  ks_red[tid >> 6][tid & 63] = ksum_loc;
  __syncthreads();
  if (tid < 64) {
    float r = ks_red[0][tid] + ks_red[1][tid] + ks_red[2][tid] + ks_red[3][tid];
    ksp[((size_t)hh * 16 + s) * 64 + tid] = r;
  }
}

// ---------------- K3: reduce split partials -> kv^T bf16 ([hh][e][d]) + ksum f32 -------
__global__ void k_reduce(const float* __restrict__ kvp, const float* __restrict__ ksp,
                         u16* __restrict__ kvb, float* __restrict__ ksum) {
  int hh = blockIdx.x;
  int sl = blockIdx.y;                // 0..7
  int tid = threadIdx.x;
  for (int j = 0; j < 2; ++j) {
    int idx = sl * 512 + tid + 256 * j;     // d*64+e
    float a = 0;
    for (int s = 0; s < 16; ++s) a += kvp[((size_t)hh * 16 + s) * 4096 + idx];
    int d = idx >> 6, e = idx & 63;
    kvb[(size_t)hh * 4096 + e * 64 + d] = f2bf(a);   // store transposed for B-fragments
  }
  if (sl == 0 && tid < 64) {
    float a = 0;
    for (int s = 0; s < 16; ++s) a += ksp[((size_t)hh * 16 + s) * 64 + tid];
    ksum[hh * 64 + tid] = a;
  }
}

// ---------------- K4: attn[t][512] = (q @ kv) / (q . ksum + eps), bf16 -----------------
__global__ __launch_bounds__(256) void k_attn(const u16* __restrict__ qkv,
    const u16* __restrict__ kvb, const float* __restrict__ ksum,
    u16* __restrict__ attn) {
  __shared__ u16 qf[32][520];
  __shared__ float zl[32][8];
  __shared__ float kss[8][64];
  int tid = threadIdx.x;
  int lane = tid & 63, w = tid >> 6;
  size_t t0 = (size_t)blockIdx.x * 32;
  int b = (int)(t0 >> 13);
  for (int jj = 0; jj < 16; ++jj) {
    int id = tid + 256 * jj;          // 0..4095
    int row = id >> 7, cq = id & 127;
    *reinterpret_cast<ushort4*>(&qf[row][cq * 4]) =
        *reinterpret_cast<const ushort4*>(&qkv[(t0 + row) * 1536 + cq * 4]);
  }
  { int i = tid, i2 = tid + 256;       // stage 512 ksum floats
    kss[i >> 6][i & 63]   = ksum[b * 512 + i];
    kss[i2 >> 6][i2 & 63] = ksum[b * 512 + i2]; }
  __syncthreads();
  {   // z per (token, head) — vectorized short8 reads
    int tok = tid & 31, h = tid >> 5;
    float z = 0;
    for (int jq = 0; jq < 8; ++jq) {
      short8 qv = *reinterpret_cast<const short8*>(&qf[tok][h * 64 + jq * 8]);
      for (int e = 0; e < 8; ++e) z += bf2f((u16)qv[e]) * kss[h][jq * 8 + e];
    }
    zl[tok][h] = z + 1e-6f;
  }
  __syncthreads();
  for (int hi = 0; hi < 2; ++hi) {
    int h = w * 2 + hi;
    size_t kvoff = (size_t)(b * 8 + h) * 4096;
    f32x4 acc[2][4];
    for (int m = 0; m < 2; ++m) for (int n = 0; n < 4; ++n) acc[m][n] = (f32x4)0.0f;
    for (int kk = 0; kk < 2; ++kk) {
      int kb = kk * 32 + 8 * (lane >> 4);
      short8 af[2], bfr[4];
      for (int m = 0; m < 2; ++m)
        af[m] = *reinterpret_cast<const short8*>(&qf[m * 16 + (lane & 15)][h * 64 + kb]);
      for (int n = 0; n < 4; ++n)
        bfr[n] = *reinterpret_cast<const short8*>(&kvb[kvoff + (size_t)(n * 16 + (lane & 15)) * 64 + kb]);
      for (int m = 0; m < 2; ++m)
        for (int n = 0; n < 4; ++n)
          acc[m][n] = __builtin_amdgcn_mfma_f32_16x16x32_bf16(af[m], bfr[n], acc[m][n], 0, 0, 0);
    }
    for (int m = 0; m < 2; ++m) {
      int tokb = m * 16 + (lane >> 4) * 4;
      for (int n = 0; n < 4; ++n) {
        int e = n * 16 + (lane & 15);
        for (int j = 0; j < 4; ++j) {
          float vv = acc[m][n][j] / zl[tokb + j][h];
          attn[(t0 + tokb + j) * 512 + h * 64 + e] = f2bf(vv);
        }
      }
    }
  }
}

extern "C" void kernel_launch(void* const* d_in, const int* in_sizes, int n_in,
                              void* d_out, int out_size, void* d_ws, size_t ws_size,
                              hipStream_t stream) {
  const float* x  = (const float*)d_in[0];
  const float* Wq = (const float*)d_in[1];
  const float* bq = (const float*)d_in[2];
  const float* Wk = (const float*)d_in[3];
  const float* bk = (const float*)d_in[4];
  const float* Wv = (const float*)d_in[5];
  const float* bv = (const float*)d_in[6];
  const float* Wo = (const float*)d_in[7];
  const float* bo = (const float*)d_in[8];
  float* out = (float*)d_out;

  char* ws = (char*)d_ws;
  u16*   Wcat = (u16*)(ws + 0);                 //   2,097,152 B
  u16*   qkv  = (u16*)(ws + 2097152);           // 100,663,296 B
  // Region at 102,760,448 is time-shared (strict stream order):
  //   xb   (33.5 MB)  written by k_prep, read by gemm<0>
  //   kvp  ( 8.4 MB)  written by kvstats (after gemm<0>), read by reduce
  //   attn (33.5 MB)  written by k_attn (after reduce), read by gemm<1>
  u16*   xb   = (u16*)(ws + 102760448);
  float* kvp  = (float*)(ws + 102760448);
  u16*   attn = (u16*)(ws + 102760448);
  float* ksp  = (float*)(ws + 136314880);       //     131,072 B
  u16*   kvb  = (u16*)(ws + 136445952);         //     262,144 B
  float* ksum = (float*)(ws + 136708096);       //       8,192 B   (peak ~130.4 MiB)

  k_prep   <<<4096, 256, 0, stream>>>(x, Wq, Wk, Wv, Wo, Wcat, xb);
  k_gemm<0><<<3072, 256, 0, stream>>>(xb, Wcat, bq, bk, bv, qkv, nullptr);
  k_kvstats<<<dim3(32, 16), 256, 0, stream>>>(qkv, kvp, ksp);
  k_reduce <<<dim3(32, 8), 256, 0, stream>>>(kvp, ksp, kvb, ksum);
  k_attn   <<<1024, 256, 0, stream>>>(qkv, kvb, ksum, attn);
  k_gemm<1><<<1024, 256, 0, stream>>>(attn, Wcat, bo, nullptr, nullptr, nullptr, out);
}